// Round 10
// baseline (587.243 us; speedup 1.0000x reference)
//
#include <hip/hip_runtime.h>

#define BN_EPS 1e-5f
#define BSHIFT 9              // nodes per bin = 512
#define BINCAP 10240          // >22 sigma above mean 8192 edges/bin
#define T_SCALE 16.0f
#define T_INV_SCALE (1.0f / 16.0f)

typedef __attribute__((ext_vector_type(8))) short short8;
typedef __attribute__((ext_vector_type(4))) float floatx4;
typedef __attribute__((ext_vector_type(2))) float floatx2;

__device__ inline unsigned short f2bf(float x) {
  unsigned int u = __float_as_uint(x);
  u += 0x7fffu + ((u >> 16) & 1u);
  return (unsigned short)(u >> 16);
}
__device__ inline float bflo(unsigned int v) { return __uint_as_float(v << 16); }
__device__ inline float bfhi(unsigned int v) { return __uint_as_float(v & 0xffff0000u); }
__device__ inline unsigned char f2fp8(float x) {
  return (unsigned char)(__builtin_amdgcn_cvt_pk_fp8_f32(x, x, 0, false) & 0xff);
}

// ---------------- f32 -> bf16 array ----------------
__global__ void k_f2bf_arr(const float* __restrict__ in, unsigned short* __restrict__ out,
                           long long n8) {
  long long i = blockIdx.x * 256LL + threadIdx.x;
  if (i < n8) {
    float4 a = *(const float4*)(in + i * 8);
    float4 b = *(const float4*)(in + i * 8 + 4);
    ushort4 lo, hi;
    lo.x = f2bf(a.x); lo.y = f2bf(a.y); lo.z = f2bf(a.z); lo.w = f2bf(a.w);
    hi.x = f2bf(b.x); hi.y = f2bf(b.y); hi.z = f2bf(b.z); hi.w = f2bf(b.w);
    *(ushort4*)(out + i * 8) = lo;
    *(ushort4*)(out + i * 8 + 4) = hi;
  }
}

// ---------------- weight pack: W[128][128] f32 -> bf16 fragment layout ----------------
__global__ void k_wpack(const float* __restrict__ W, unsigned short* __restrict__ Wp) {
  int o = blockIdx.x * 256 + threadIdx.x;
  int j = o & 7, l = (o >> 3) & 63, cf = (o >> 9) & 7, ks = o >> 12;
  int k = ks * 32 + (l >> 4) * 8 + j;
  int col = cf * 16 + (l & 15);
  Wp[o] = f2bf(W[k * 128 + col]);
}

// ---------------- CSR build: atomic-free binned counting sort ----------------
// packed entry: (dst & 511) << 23 | src   (valid for N < 2^23)
__global__ __launch_bounds__(1024) void k_bin_pairs(
    const int* __restrict__ src, const int* __restrict__ dst,
    int* __restrict__ binCount, unsigned int* __restrict__ binbuf, int E, int nbins) {
  __shared__ int hist[256], base[256];
  int tid = threadIdx.x;
  int b0 = blockIdx.x * 8192;
  if (tid < 256) hist[tid] = 0;
  __syncthreads();
  int s[8], d[8], rk[8], bn[8];
  #pragma unroll
  for (int i = 0; i < 8; i++) {
    int e = b0 + tid + i * 1024;
    if (e < E) {
      s[i] = src[e];
      d[i] = dst[e];
      bn[i] = d[i] >> BSHIFT;
      rk[i] = atomicAdd(&hist[bn[i]], 1);
    }
  }
  __syncthreads();
  if (tid < nbins && hist[tid] > 0)
    base[tid] = atomicAdd(&binCount[tid], hist[tid]);
  __syncthreads();
  #pragma unroll
  for (int i = 0; i < 8; i++) {
    int e = b0 + tid + i * 1024;
    if (e < E)
      binbuf[(size_t)bn[i] * BINCAP + base[bn[i]] + rk[i]] =
          ((unsigned)(d[i] & 511) << 23) | (unsigned)s[i];
  }
}

__global__ void k_binscan(const int* __restrict__ binCount, int* __restrict__ binBase,
                          int* __restrict__ row_ptr, int nbins, int N, int E) {
  __shared__ int sd[256];
  int tid = threadIdx.x;
  int v = (tid < nbins) ? binCount[tid] : 0;
  sd[tid] = v;
  __syncthreads();
  for (int off = 1; off < 256; off <<= 1) {
    int t = (tid >= off) ? sd[tid - off] : 0;
    __syncthreads();
    sd[tid] += t;
    __syncthreads();
  }
  if (tid < nbins) binBase[tid] = sd[tid] - v;
  if (tid == nbins) binBase[nbins] = sd[nbins - 1];
  if (tid == 0) row_ptr[N] = E;
}

__global__ __launch_bounds__(1024) void k_csr_bin(
    const unsigned int* __restrict__ binbuf, const int* __restrict__ binCount,
    const int* __restrict__ binBase, int* __restrict__ row_ptr,
    int* __restrict__ csr, int N) {
  __shared__ int hist[512];
  __shared__ int incl[512];
  int b = blockIdx.x;
  int tid = threadIdx.x;
  int nE = binCount[b];
  int eb = binBase[b];
  const unsigned int* p = binbuf + (size_t)b * BINCAP;
  if (tid < 512) hist[tid] = 0;
  __syncthreads();
  for (int e = tid; e < nE; e += 1024) {
    int dl = (int)(p[e] >> 23);
    atomicAdd(&hist[dl], 1);
  }
  __syncthreads();
  if (tid < 512) incl[tid] = hist[tid];
  __syncthreads();
  for (int off = 1; off < 512; off <<= 1) {
    int t = 0;
    if (tid < 512 && tid >= off) t = incl[tid - off];
    __syncthreads();
    if (tid < 512) incl[tid] += t;
    __syncthreads();
  }
  int node0 = b << BSHIFT;
  if (tid < 512) {
    int ex = incl[tid] - hist[tid];
    if (node0 + tid < N) row_ptr[node0 + tid] = eb + ex;
    hist[tid] = ex;             // reuse as bin-local cursor
  }
  __syncthreads();
  for (int e = tid; e < nE; e += 1024) {
    unsigned int pr = p[e];
    int dl = (int)(pr >> 23);
    int sv = (int)(pr & 0x7fffffu);
    int r = atomicAdd(&hist[dl], 1);
    csr[eb + r] = sv;
  }
}

// ---------------- fused BN(+ReLU) -> dual MFMA GEMM (bf16 in; T fp8 x16, R bf16) ----------------
__global__ __launch_bounds__(256) void k_bn_gemm_dual(
    const unsigned short* __restrict__ Hb, const unsigned short* __restrict__ Wlp,
    const unsigned short* __restrict__ Wrp, const float* __restrict__ bias,
    const float* __restrict__ stats, const float* __restrict__ gamma,
    const float* __restrict__ beta, unsigned char* __restrict__ Tq,
    unsigned short* __restrict__ Rb, int n, int apply_bn) {
  __shared__ unsigned int As[64 * 64];   // 64 rows x 128 bf16, XOR-swizzled
  __shared__ float sc[128], sh[128];
  int tid = threadIdx.x;
  if (tid < 128) {
    if (apply_bn) {
      float invn = 1.0f / (float)n;
      float mu = stats[tid] * invn;
      float var = stats[128 + tid] * invn - mu * mu;
      float s = rsqrtf(var + BN_EPS) * gamma[tid];
      sc[tid] = s;
      sh[tid] = beta[tid] - mu * s;
    }
  }
  __syncthreads();

  int row0 = blockIdx.x * 64;
  {
    int r = tid >> 2, cbase = (tid & 3) * 32;
    const unsigned short* srcp = Hb + (size_t)(row0 + r) * 128 + cbase;
    bool valid = (row0 + r) < n;
    unsigned int swz = (unsigned)((r & 7) << 2);
    unsigned int ubase = (unsigned)(r * 64 + (cbase >> 1));
    #pragma unroll
    for (int m = 0; m < 4; m++) {
      uint4 raw = make_uint4(0u, 0u, 0u, 0u);
      if (valid) raw = *(const uint4*)(srcp + m * 8);
      uint4 pk;
      if (apply_bn) {
        int c = cbase + m * 8;
        float f0 = fmaxf(bflo(raw.x) * sc[c + 0] + sh[c + 0], 0.f);
        float f1 = fmaxf(bfhi(raw.x) * sc[c + 1] + sh[c + 1], 0.f);
        float f2 = fmaxf(bflo(raw.y) * sc[c + 2] + sh[c + 2], 0.f);
        float f3 = fmaxf(bfhi(raw.y) * sc[c + 3] + sh[c + 3], 0.f);
        float f4 = fmaxf(bflo(raw.z) * sc[c + 4] + sh[c + 4], 0.f);
        float f5 = fmaxf(bfhi(raw.z) * sc[c + 5] + sh[c + 5], 0.f);
        float f6 = fmaxf(bflo(raw.w) * sc[c + 6] + sh[c + 6], 0.f);
        float f7 = fmaxf(bfhi(raw.w) * sc[c + 7] + sh[c + 7], 0.f);
        pk.x = (unsigned)f2bf(f0) | ((unsigned)f2bf(f1) << 16);
        pk.y = (unsigned)f2bf(f2) | ((unsigned)f2bf(f3) << 16);
        pk.z = (unsigned)f2bf(f4) | ((unsigned)f2bf(f5) << 16);
        pk.w = (unsigned)f2bf(f6) | ((unsigned)f2bf(f7) << 16);
      } else {
        pk = raw;   // x already bf16, no BN on layer 0
      }
      *(uint4*)(As + ((ubase + m * 4) ^ swz)) = pk;
    }
  }
  __syncthreads();

  int w = tid >> 6, lane = tid & 63;
  int wrow = (w << 4) + (lane & 15);
  unsigned int aswz = (unsigned)((wrow & 7) << 2);
  floatx4 accT[8] = {}, accR[8] = {};

  #pragma unroll
  for (int ks = 0; ks < 4; ks++) {
    unsigned int aoff = (unsigned)(wrow * 64 + ks * 16 + ((lane >> 4) << 2)) ^ aswz;
    short8 a = *(const short8*)(As + aoff);
    #pragma unroll
    for (int cf = 0; cf < 8; cf++) {
      int wo = ((ks * 8 + cf) * 64 + lane) * 8;
      short8 wl = *(const short8*)(Wlp + wo);
      short8 wr = *(const short8*)(Wrp + wo);
      accT[cf] = __builtin_amdgcn_mfma_f32_16x16x32_bf16(a, wl, accT[cf], 0, 0, 0);
      accR[cf] = __builtin_amdgcn_mfma_f32_16x16x32_bf16(a, wr, accR[cf], 0, 0, 0);
    }
  }

  int colb = lane & 15;
  int rb = row0 + (w << 4) + ((lane >> 4) << 2);
  #pragma unroll
  for (int cf = 0; cf < 8; cf++) {
    int col = cf * 16 + colb;
    float bv = bias[col];
    #pragma unroll
    for (int i = 0; i < 4; i++) {
      int r = rb + i;
      if (r < n) {
        Tq[(size_t)r * 128 + col] = f2fp8(accT[cf][i] * T_SCALE);
        Rb[(size_t)r * 128 + col] = f2bf(accR[cf][i] + bv);
      }
    }
  }
}

// ---------------- aggregate: Hb[i] = bf16(Rb[i] + mean_{j in N(i)} T[j]); BN stats ----------------
// Node-pair per wave. Indices come from WAVE-UNIFORM scalar loads (no ds_bpermute
// in the address chain); gather address = cndmask(even,odd) by half-wave.
// First 32 edges of BOTH nodes issued as one 32-load burst; deg>32 tail is rare.
__global__ __launch_bounds__(256) void k_aggregate(
    const unsigned char* __restrict__ Tq, const unsigned short* __restrict__ Rb,
    unsigned short* __restrict__ Hb, const int* __restrict__ row_ptr,
    const int* __restrict__ csr, float* __restrict__ stats, int n) {
  __shared__ float sred[4][256];
  int tid = threadIdx.x;
  int lane = tid & 63;
  int half = lane >> 5;
  int sl = lane & 31;            // features sl*4 .. sl*4+3
  int wlocal = tid >> 6;
  int wid = __builtin_amdgcn_readfirstlane((int)((blockIdx.x * blockDim.x + tid) >> 6));
  int nw = (gridDim.x * blockDim.x) >> 6;
  float s0 = 0, s1 = 0, s2 = 0, s3 = 0, q0 = 0, q1 = 0, q2 = 0, q3 = 0;

  for (int p = wid; 2 * p < n; p += nw) {
    int i2 = 2 * p;
    int r0 = __builtin_amdgcn_readfirstlane(row_ptr[i2]);
    int r1 = __builtin_amdgcn_readfirstlane(row_ptr[i2 + 1]);
    bool hasB = (i2 + 1 < n);
    int r2 = hasB ? __builtin_amdgcn_readfirstlane(row_ptr[i2 + 2]) : r1;
    int cA = r1 - r0;
    int cB = r2 - r1;

    // ---- burst: first 32 edges of A and of B, 32 loads in flight ----
    unsigned dA0[8], dB0[8], dA1[8], dB1[8];
    #pragma unroll
    for (int m = 0; m < 8; m++) {
      int j0 = csr[r0 + 2 * m], j1 = csr[r0 + 2 * m + 1];   // uniform (scalar) loads
      int j = half ? j1 : j0;
      dA0[m] = (2 * m < cA) ? *(const unsigned*)(Tq + (size_t)j * 128 + sl * 4) : 0u;
    }
    #pragma unroll
    for (int m = 0; m < 8; m++) {
      int j0 = csr[r1 + 2 * m], j1 = csr[r1 + 2 * m + 1];
      int j = half ? j1 : j0;
      dB0[m] = (2 * m < cB) ? *(const unsigned*)(Tq + (size_t)j * 128 + sl * 4) : 0u;
    }
    #pragma unroll
    for (int m = 0; m < 8; m++) {
      int e = 16 + 2 * m;
      int j0 = csr[r0 + e], j1 = csr[r0 + e + 1];
      int j = half ? j1 : j0;
      dA1[m] = (e < cA) ? *(const unsigned*)(Tq + (size_t)j * 128 + sl * 4) : 0u;
    }
    #pragma unroll
    for (int m = 0; m < 8; m++) {
      int e = 16 + 2 * m;
      int j0 = csr[r1 + e], j1 = csr[r1 + e + 1];
      int j = half ? j1 : j0;
      dB1[m] = (e < cB) ? *(const unsigned*)(Tq + (size_t)j * 128 + sl * 4) : 0u;
    }
    uint2 rvA = make_uint2(0u, 0u), rvB = make_uint2(0u, 0u);
    if (half == 0) {
      rvA = *(const uint2*)(Rb + (size_t)i2 * 128 + sl * 4);
      if (hasB) rvB = *(const uint2*)(Rb + (size_t)(i2 + 1) * 128 + sl * 4);
    }

    // ---- accumulate A ----
    float a0 = 0, a1 = 0, a2 = 0, a3 = 0;
    #pragma unroll
    for (int m = 0; m < 8; m++) {
      if (2 * m + half < cA) {
        floatx2 lo = __builtin_amdgcn_cvt_pk_f32_fp8(dA0[m], false);
        floatx2 hi = __builtin_amdgcn_cvt_pk_f32_fp8(dA0[m], true);
        a0 += lo.x; a1 += lo.y; a2 += hi.x; a3 += hi.y;
      }
    }
    #pragma unroll
    for (int m = 0; m < 8; m++) {
      if (16 + 2 * m + half < cA) {
        floatx2 lo = __builtin_amdgcn_cvt_pk_f32_fp8(dA1[m], false);
        floatx2 hi = __builtin_amdgcn_cvt_pk_f32_fp8(dA1[m], true);
        a0 += lo.x; a1 += lo.y; a2 += hi.x; a3 += hi.y;
      }
    }
    for (int k = 32; k < cA; k += 16) {   // deg>32: rare
      #pragma unroll
      for (int m = 0; m < 8; m++) {
        int e = k + 2 * m;
        int j0 = csr[r0 + e], j1 = csr[r0 + e + 1];
        int j = half ? j1 : j0;
        unsigned v = (e + half < cA) ? *(const unsigned*)(Tq + (size_t)j * 128 + sl * 4) : 0u;
        floatx2 lo = __builtin_amdgcn_cvt_pk_f32_fp8(v, false);
        floatx2 hi = __builtin_amdgcn_cvt_pk_f32_fp8(v, true);
        a0 += lo.x; a1 += lo.y; a2 += hi.x; a3 += hi.y;
      }
    }
    a0 += __shfl_xor(a0, 32);
    a1 += __shfl_xor(a1, 32);
    a2 += __shfl_xor(a2, 32);
    a3 += __shfl_xor(a3, 32);
    if (half == 0) {
      float inv = (cA > 0) ? (T_INV_SCALE / (float)cA) : 0.0f;
      float h0 = bflo(rvA.x) + a0 * inv;
      float h1 = bfhi(rvA.x) + a1 * inv;
      float h2 = bflo(rvA.y) + a2 * inv;
      float h3 = bfhi(rvA.y) + a3 * inv;
      uint2 pk;
      pk.x = (unsigned)f2bf(h0) | ((unsigned)f2bf(h1) << 16);
      pk.y = (unsigned)f2bf(h2) | ((unsigned)f2bf(h3) << 16);
      *(uint2*)(Hb + (size_t)i2 * 128 + sl * 4) = pk;
      s0 += h0; s1 += h1; s2 += h2; s3 += h3;
      q0 += h0 * h0; q1 += h1 * h1; q2 += h2 * h2; q3 += h3 * h3;
    }

    // ---- accumulate B ----
    if (hasB) {
      float b0 = 0, b1 = 0, b2 = 0, b3 = 0;
      #pragma unroll
      for (int m = 0; m < 8; m++) {
        if (2 * m + half < cB) {
          floatx2 lo = __builtin_amdgcn_cvt_pk_f32_fp8(dB0[m], false);
          floatx2 hi = __builtin_amdgcn_cvt_pk_f32_fp8(dB0[m], true);
          b0 += lo.x; b1 += lo.y; b2 += hi.x; b3 += hi.y;
        }
      }
      #pragma unroll
      for (int m = 0; m < 8; m++) {
        if (16 + 2 * m + half < cB) {
          floatx2 lo = __builtin_amdgcn_cvt_pk_f32_fp8(dB1[m], false);
          floatx2 hi = __builtin_amdgcn_cvt_pk_f32_fp8(dB1[m], true);
          b0 += lo.x; b1 += lo.y; b2 += hi.x; b3 += hi.y;
        }
      }
      for (int k = 32; k < cB; k += 16) {   // deg>32: rare
        #pragma unroll
        for (int m = 0; m < 8; m++) {
          int e = k + 2 * m;
          int j0 = csr[r1 + e], j1 = csr[r1 + e + 1];
          int j = half ? j1 : j0;
          unsigned v = (e + half < cB) ? *(const unsigned*)(Tq + (size_t)j * 128 + sl * 4) : 0u;
          floatx2 lo = __builtin_amdgcn_cvt_pk_f32_fp8(v, false);
          floatx2 hi = __builtin_amdgcn_cvt_pk_f32_fp8(v, true);
          b0 += lo.x; b1 += lo.y; b2 += hi.x; b3 += hi.y;
        }
      }
      b0 += __shfl_xor(b0, 32);
      b1 += __shfl_xor(b1, 32);
      b2 += __shfl_xor(b2, 32);
      b3 += __shfl_xor(b3, 32);
      if (half == 0) {
        float inv = (cB > 0) ? (T_INV_SCALE / (float)cB) : 0.0f;
        float h0 = bflo(rvB.x) + b0 * inv;
        float h1 = bfhi(rvB.x) + b1 * inv;
        float h2 = bflo(rvB.y) + b2 * inv;
        float h3 = bfhi(rvB.y) + b3 * inv;
        uint2 pk;
        pk.x = (unsigned)f2bf(h0) | ((unsigned)f2bf(h1) << 16);
        pk.y = (unsigned)f2bf(h2) | ((unsigned)f2bf(h3) << 16);
        *(uint2*)(Hb + (size_t)(i2 + 1) * 128 + sl * 4) = pk;
        s0 += h0; s1 += h1; s2 += h2; s3 += h3;
        q0 += h0 * h0; q1 += h1 * h1; q2 += h2 * h2; q3 += h3 * h3;
      }
    }
  }

  if (half == 0) {
    sred[wlocal][sl * 8 + 0] = s0; sred[wlocal][sl * 8 + 1] = s1;
    sred[wlocal][sl * 8 + 2] = s2; sred[wlocal][sl * 8 + 3] = s3;
    sred[wlocal][sl * 8 + 4] = q0; sred[wlocal][sl * 8 + 5] = q1;
    sred[wlocal][sl * 8 + 6] = q2; sred[wlocal][sl * 8 + 7] = q3;
  }
  __syncthreads();
  float tot = sred[0][tid] + sred[1][tid] + sred[2][tid] + sred[3][tid];
  int slx = tid >> 3, k2f = tid & 7;
  int f = slx * 4 + (k2f & 3);
  int idx = (k2f >> 2) ? (128 + f) : f;
  atomicAdd(&stats[idx], tot);
}

// ---------------- final: Out = bn_relu(Hb) @ Wout + bout ----------------
__global__ __launch_bounds__(256) void k_gemm_out(
    const unsigned short* __restrict__ Hb, const float* __restrict__ W,
    const float* __restrict__ bias, const float* __restrict__ stats,
    const float* __restrict__ gamma, const float* __restrict__ beta,
    float* __restrict__ Out, int nrows) {
  __shared__ float As[64 * 132];
  __shared__ float sc[128], sh[128];
  int tid = threadIdx.x;
  if (tid < 128) {
    float invn = 1.0f / (float)nrows;
    float mu = stats[tid] * invn;
    float var = stats[128 + tid] * invn - mu * mu;
    float s = rsqrtf(var + BN_EPS) * gamma[tid];
    sc[tid] = s;
    sh[tid] = beta[tid] - mu * s;
  }
  __syncthreads();
  int row0 = blockIdx.x * 64;
  #pragma unroll
  for (int i = 0; i < 4; i++) {
    int g = tid + i * 256;
    int r = g >> 4;
    int c8 = g & 15;
    uint4 raw = make_uint4(0u, 0u, 0u, 0u);
    if (row0 + r < nrows)
      raw = *(const uint4*)(Hb + (size_t)(row0 + r) * 128 + c8 * 8);
    int c = c8 * 8;
    float* dstp = As + r * 132 + c;
    dstp[0] = fmaxf(bflo(raw.x) * sc[c + 0] + sh[c + 0], 0.f);
    dstp[1] = fmaxf(bfhi(raw.x) * sc[c + 1] + sh[c + 1], 0.f);
    dstp[2] = fmaxf(bflo(raw.y) * sc[c + 2] + sh[c + 2], 0.f);
    dstp[3] = fmaxf(bfhi(raw.y) * sc[c + 3] + sh[c + 3], 0.f);
    dstp[4] = fmaxf(bflo(raw.z) * sc[c + 4] + sh[c + 4], 0.f);
    dstp[5] = fmaxf(bfhi(raw.z) * sc[c + 5] + sh[c + 5], 0.f);
    dstp[6] = fmaxf(bflo(raw.w) * sc[c + 6] + sh[c + 6], 0.f);
    dstp[7] = fmaxf(bfhi(raw.w) * sc[c + 7] + sh[c + 7], 0.f);
  }
  __syncthreads();

  int cg = tid & 7;
  int rg = tid >> 3;
  float acc[2][4] = {};
  for (int k = 0; k < 128; k++) {
    float4 w = *(const float4*)(W + k * 32 + cg * 4);
    float a0 = As[(rg * 2 + 0) * 132 + k];
    float a1 = As[(rg * 2 + 1) * 132 + k];
    acc[0][0] += a0 * w.x; acc[0][1] += a0 * w.y; acc[0][2] += a0 * w.z; acc[0][3] += a0 * w.w;
    acc[1][0] += a1 * w.x; acc[1][1] += a1 * w.y; acc[1][2] += a1 * w.z; acc[1][3] += a1 * w.w;
  }
  float4 bv = *(const float4*)(bias + cg * 4);
  #pragma unroll
  for (int i = 0; i < 2; i++) {
    int r = row0 + rg * 2 + i;
    if (r < nrows) {
      float4 o = make_float4(acc[i][0] + bv.x, acc[i][1] + bv.y,
                             acc[i][2] + bv.z, acc[i][3] + bv.w);
      *(float4*)(Out + (size_t)r * 32 + cg * 4) = o;
    }
  }
}

extern "C" void kernel_launch(void* const* d_in, const int* in_sizes, int n_in,
                              void* d_out, int out_size, void* d_ws, size_t ws_size,
                              hipStream_t stream) {
  const float* x    = (const float*)d_in[0];
  const int*   e_sp = (const int*)d_in[1];
  const int*   e_tp = (const int*)d_in[2];
  const float* Wl[4]  = {(const float*)d_in[3],  (const float*)d_in[8],
                         (const float*)d_in[13], (const float*)d_in[18]};
  const float* Wr[4]  = {(const float*)d_in[4],  (const float*)d_in[9],
                         (const float*)d_in[14], (const float*)d_in[19]};
  const float* bb[4]  = {(const float*)d_in[5],  (const float*)d_in[10],
                         (const float*)d_in[15], (const float*)d_in[20]};
  const float* gm[4]  = {(const float*)d_in[6],  (const float*)d_in[11],
                         (const float*)d_in[16], (const float*)d_in[21]};
  const float* bt[4]  = {(const float*)d_in[7],  (const float*)d_in[12],
                         (const float*)d_in[17], (const float*)d_in[22]};
  const float* Wout = (const float*)d_in[23];
  const float* bout = (const float*)d_in[24];

  const int N = in_sizes[0] / 128;
  const int E = in_sizes[1] / 2;
  const int nbins = (N + ((1 << BSHIFT) - 1)) >> BSHIFT;   // 196 for N=100000

  char* ws = (char*)d_ws;
  size_t off = 0;
  auto alloc = [&](size_t bytes) {
    void* p = ws + off;
    off += (bytes + 255) & ~(size_t)255;
    return p;
  };
  unsigned short* Hb = (unsigned short*)alloc((size_t)N * 128 * 2);  // h (bf16)
  unsigned short* xb = (unsigned short*)alloc((size_t)N * 128 * 2);  // x (bf16)
  unsigned short* Rb = (unsigned short*)alloc((size_t)N * 128 * 2);  // r (bf16)
  unsigned char*  Tq = (unsigned char*)alloc((size_t)N * 128);       // t (fp8 e4m3, x16)
  int* row_sp    = (int*)alloc((size_t)(N + 1) * 4);
  int* row_tp    = (int*)alloc((size_t)(N + 1) * 4);
  int* csr_sp    = (int*)alloc((size_t)(E + 64) * 4);   // +64 pad: uniform overreads safe
  int* csr_tp    = (int*)alloc((size_t)(E + 64) * 4);
  unsigned int* binbuf = (unsigned int*)alloc((size_t)256 * BINCAP * 4);  // 10.5 MB
  int* binCount  = (int*)alloc(256 * 4);
  int* binBase   = (int*)alloc(257 * 4);
  float* statsB  = (float*)alloc(4 * 256 * 4);
  unsigned short* Wlp[4], *Wrp[4];
  for (int l = 0; l < 4; l++) {
    Wlp[l] = (unsigned short*)alloc(16384 * 2);
    Wrp[l] = (unsigned short*)alloc(16384 * 2);
  }

  const int pb = (E + 8191) / 8192;

  for (int l = 0; l < 4; l++) {
    k_wpack<<<64, 256, 0, stream>>>(Wl[l], Wlp[l]);
    k_wpack<<<64, 256, 0, stream>>>(Wr[l], Wrp[l]);
  }
  k_f2bf_arr<<<(int)(((size_t)N * 16 + 255) / 256), 256, 0, stream>>>(x, xb, (size_t)N * 16);
  hipMemsetAsync(statsB, 0, 4 * 256 * 4, stream);

  // ---- build CSR (spatial) ----
  hipMemsetAsync(binCount, 0, 256 * 4, stream);
  k_bin_pairs<<<pb, 1024, 0, stream>>>(e_sp, e_sp + E, binCount, binbuf, E, nbins);
  k_binscan<<<1, 256, 0, stream>>>(binCount, binBase, row_sp, nbins, N, E);
  k_csr_bin<<<nbins, 1024, 0, stream>>>(binbuf, binCount, binBase, row_sp, csr_sp, N);

  // ---- build CSR (temporal) ----
  hipMemsetAsync(binCount, 0, 256 * 4, stream);
  k_bin_pairs<<<pb, 1024, 0, stream>>>(e_tp, e_tp + E, binCount, binbuf, E, nbins);
  k_binscan<<<1, 256, 0, stream>>>(binCount, binBase, row_tp, nbins, N, E);
  k_csr_bin<<<nbins, 1024, 0, stream>>>(binbuf, binCount, binBase, row_tp, csr_tp, N);

  const int* rowp[4] = {row_sp, row_sp, row_tp, row_tp};
  const int* csr[4]  = {csr_sp, csr_sp, csr_tp, csr_tp};

  const int gblocks = (N + 63) / 64;
  const unsigned short* cur = xb;
  for (int l = 0; l < 4; l++) {
    const float* st = (l == 0) ? statsB : (statsB + (l - 1) * 256);
    const float* g  = (l == 0) ? gm[0] : gm[l - 1];
    const float* be = (l == 0) ? bt[0] : bt[l - 1];
    k_bn_gemm_dual<<<gblocks, 256, 0, stream>>>(cur, Wlp[l], Wrp[l], bb[l],
                                                st, g, be, Tq, Rb, N, l == 0 ? 0 : 1);
    k_aggregate<<<2048, 256, 0, stream>>>(Tq, Rb, Hb, rowp[l], csr[l],
                                          statsB + l * 256, N);
    cur = Hb;
  }
  k_gemm_out<<<gblocks, 256, 0, stream>>>(Hb, Wout, bout, statsB + 3 * 256,
                                          gm[3], bt[3], (float*)d_out, N);
}